// Round 1
// baseline (708.129 us; speedup 1.0000x reference)
//
#include <hip/hip_runtime.h>

// MaxPool2d 2x2 stride 2, no padding.
// Input  (32, 64, 256, 256) fp32  -> flat (2048, 256, 256)
// Output (32, 64, 128, 128) fp32  -> flat (2048, 128, 128)
//
// Memory-bound: 512 MiB read + 128 MiB write => ~107 us at 6.3 TB/s.
// Each thread computes 4 contiguous output pixels:
//   2x float4 loads from input row 2*oy, 2x from row 2*oy+1, 1x float4 store.

__global__ __launch_bounds__(256) void MaxPool2d_53901839564893_kernel(
    const float* __restrict__ in, float* __restrict__ out, int total_vec) {
    // total_vec = number of float4 output groups = out_size / 4
    const long long stride = (long long)gridDim.x * blockDim.x;
    for (long long idx = (long long)blockIdx.x * blockDim.x + threadIdx.x;
         idx < total_vec; idx += stride) {
        // 128-wide output rows -> 32 float4-groups per row
        const long long row = idx >> 5;      // global output row (ni*128 + oy)
        const int grp      = (int)(idx & 31);  // which group-of-4 within the row
        const long long ni = row >> 7;       // image index (n*64 + c)
        const int oy       = (int)(row & 127);

        const float* r0 = in + ni * (256LL * 256) + (long long)(2 * oy) * 256 + grp * 8;
        const float* r1 = r0 + 256;

        const float4 a0 = *reinterpret_cast<const float4*>(r0);
        const float4 a1 = *reinterpret_cast<const float4*>(r0 + 4);
        const float4 b0 = *reinterpret_cast<const float4*>(r1);
        const float4 b1 = *reinterpret_cast<const float4*>(r1 + 4);

        float4 o;
        o.x = fmaxf(fmaxf(a0.x, a0.y), fmaxf(b0.x, b0.y));
        o.y = fmaxf(fmaxf(a0.z, a0.w), fmaxf(b0.z, b0.w));
        o.z = fmaxf(fmaxf(a1.x, a1.y), fmaxf(b1.x, b1.y));
        o.w = fmaxf(fmaxf(a1.z, a1.w), fmaxf(b1.z, b1.w));

        *reinterpret_cast<float4*>(out + idx * 4) = o;
    }
}

extern "C" void kernel_launch(void* const* d_in, const int* in_sizes, int n_in,
                              void* d_out, int out_size, void* d_ws, size_t ws_size,
                              hipStream_t stream) {
    const float* in = (const float*)d_in[0];
    float* out = (float*)d_out;
    const int total_vec = out_size / 4;  // 8,388,608 float4 groups

    const int block = 256;
    // Memory-bound: cap grid at ~2048 blocks (256 CU x 8), grid-stride the rest.
    int grid = (total_vec + block - 1) / block;
    if (grid > 2048) grid = 2048;

    MaxPool2d_53901839564893_kernel<<<grid, block, 0, stream>>>(in, out, total_vec);
}